// Round 7
// baseline (505.655 us; speedup 1.0000x reference)
//
#include <hip/hip_runtime.h>

#define T 512
constexpr int Bc = 512, Nc = 40, Hc = 128, FEc = 16, Mc = 128, OUTc = 128, NPASS = 3;
constexpr int ROWP = 136;   // bf16 LDS row pitch
constexpr int EPOOL = 512;  // edge pool slots (mean ~296, sigma ~22; fallback covers overflow)

typedef __attribute__((ext_vector_type(8))) short short8;
typedef __attribute__((ext_vector_type(4))) float floatx4;
typedef __attribute__((ext_vector_type(4))) float fvec4;

// ws layout (bf16 elements): fragment-major B operands, K-padded We, then per-block ep
constexpr int WS_WN = 0, WS_WM = 16384, WS_WI = 32768, WS_WH = 81920, WS_WG = 131072, WS_WO = 163840;
constexpr int WS_WE16 = 196608;           // We padded to K=32
constexpr int WS_EP   = 200704;           // ep: Bc * EPOOL * 128 bf16

__device__ __forceinline__ float fast_rcp(float x) { return __builtin_amdgcn_rcpf(x); }
__device__ __forceinline__ float fast_sigmoid(float x) { return fast_rcp(1.f + __expf(-x)); }
__device__ __forceinline__ float fast_tanh(float x) {
    float t = __expf(2.f * x);
    return 1.f - 2.f * fast_rcp(t + 1.f);
}
__device__ __forceinline__ float bf2f(unsigned short u) {
    union { unsigned int i; float f; } v; v.i = ((unsigned int)u) << 16; return v.f;
}
__device__ __forceinline__ unsigned short f2bf(float f) {
    union { float f; unsigned int i; } v; v.f = f;
    unsigned int r = v.i + 0x7fff + ((v.i >> 16) & 1);   // RNE
    return (unsigned short)(r >> 16);
}
__device__ __forceinline__ float bflo(unsigned int d) {
    union { unsigned int i; float f; } v; v.i = d << 16; return v.f;
}
__device__ __forceinline__ float bfhi(unsigned int d) {
    union { unsigned int i; float f; } v; v.i = d & 0xffff0000u; return v.f;
}

__device__ __forceinline__ floatx4 mm(short8 a, short8 b, floatx4 c) {
    return __builtin_amdgcn_mfma_f32_16x16x32_bf16(a, b, c, 0, 0, 0);
}
// A-fragment: A[m=lane&15][k=quad*8+j]; rows>=40 clamped (their C rows discarded)
__device__ __forceinline__ short8 afrag(const unsigned short* buf, int mt, int kt, int lane) {
    int row = mt * 16 + (lane & 15); row = row > 39 ? 39 : row;
    return *(const short8*)(buf + row * ROWP + kt * 32 + (lane >> 4) * 8);
}
__device__ __forceinline__ short8 bfrag(const unsigned short* w, int nt, int nKT, int kt, int lane) {
    return *(const short8*)(w + ((nt * nKT + kt) * 64 + lane) * 8);
}

// ---- prep: weights -> bf16 B-fragment layout in ws ----
__global__ void prep_kernel(const float* __restrict__ Wn, const float* __restrict__ Wm,
                            const float* __restrict__ Wi, const float* __restrict__ Wh,
                            const float* __restrict__ Wg, const float* __restrict__ Wo,
                            const float* __restrict__ We, unsigned short* __restrict__ ws) {
    int c = blockIdx.x, lane = threadIdx.x;
    int quad = lane >> 4, l16 = lane & 15;
    if (c >= 384) {          // We padded to K=32 (rows 16..31 zero)
        int nt = c - 384;
        short8 v;
#pragma unroll
        for (int j = 0; j < 8; ++j) {
            int k = quad * 8 + j;
            v[j] = (k < FEc) ? (short)f2bf(We[k * Mc + nt * 16 + l16]) : (short)0;
        }
        *(short8*)(ws + WS_WE16 + nt * 512 + lane * 8) = v;
        return;
    }
    const float* W; int N, nKT, local; unsigned short* dst;
    if (c < 32)       { W = Wn; N = 128; nKT = 4; local = c;       dst = ws + WS_WN; }
    else if (c < 64)  { W = Wm; N = 128; nKT = 4; local = c - 32;  dst = ws + WS_WM; }
    else if (c < 160) { W = Wi; N = 384; nKT = 4; local = c - 64;  dst = ws + WS_WI; }
    else if (c < 256) { W = Wh; N = 384; nKT = 4; local = c - 160; dst = ws + WS_WH; }
    else if (c < 320) { W = Wg; N = 128; nKT = 8; local = c - 256; dst = ws + WS_WG; }
    else              { W = Wo; N = 128; nKT = 8; local = c - 320; dst = ws + WS_WO; }
    int nt = local / nKT, kt = local % nKT;
    short8 v;
#pragma unroll
    for (int j = 0; j < 8; ++j) {
        int k = kt * 32 + quad * 8 + j;
        v[j] = (short)f2bf(W[k * N + nt * 16 + l16]);
    }
    *(short8*)(dst + local * 512 + lane * 8) = v;
}

// T=512, 8 waves, LDS ~62 KB -> 2 blocks/CU -> ALL 512 blocks co-resident (1 round).
template<bool USE_EP>
__global__ __launch_bounds__(T, 4) void mpnn_kernel(
    const float* __restrict__ nodes, const float* __restrict__ edges,
    const float* __restrict__ We, const float* __restrict__ bi,
    const float* __restrict__ bh, const float* __restrict__ bg,
    const float* __restrict__ bo, const unsigned short* __restrict__ ws,
    unsigned short* __restrict__ ep_g,
    float* __restrict__ out)
{
    __shared__ __attribute__((aligned(16))) unsigned short s_hb[Nc * ROWP];   // bf16 h
    __shared__ __attribute__((aligned(16))) unsigned short s_mb[Nc * ROWP];   // messages / nodes(cat)
    __shared__ __attribute__((aligned(16))) unsigned short s_npb[Nc * ROWP];  // np, then r-gate
    __shared__ __attribute__((aligned(16))) unsigned short s_eb[Nc * ROWP];   // emb, then z-gate (init: slot_src)
    __shared__ __attribute__((aligned(16))) unsigned short s_pool[EPOOL * FEc]; // 16 KB bf16 edge features
    __shared__ unsigned char s_nbr[Nc][Nc];
    __shared__ int s_cnt[Nc];
    __shared__ int s_off[Nc];
    __shared__ int s_total;

    const int b = blockIdx.x, tid = threadIdx.x;
    const int lane = tid & 63, wave = tid >> 6;          // 8 waves; nt = wave
    const int quad = lane >> 4, l16 = lane & 15;
    const int m = tid & 127, g = tid >> 7;               // attention: g in 0..3
    const int col = wave * 16 + l16;

    const float* nodes_b = nodes + (size_t)b * Nc * Hc;
    const float* edges_b = edges + (size_t)b * Nc * Nc * FEc;
    const unsigned short* wWn = ws + WS_WN; const unsigned short* wWm = ws + WS_WM;
    const unsigned short* wWi = ws + WS_WI; const unsigned short* wWh = ws + WS_WH;
    const unsigned short* wWg = ws + WS_WG; const unsigned short* wWo = ws + WS_WO;
    unsigned short* epb = ep_g + (size_t)b * EPOOL * Mc;

    // ---- init: h fp32 in registers (static map), bf16 in LDS ----
    float hreg[3][4];
#pragma unroll
    for (int mt = 0; mt < 3; ++mt)
#pragma unroll
        for (int reg = 0; reg < 4; ++reg) {
            int row = mt * 16 + quad * 4 + reg;
            float v = (row < Nc) ? nodes_b[row * Hc + col] : 0.f;
            hreg[mt][reg] = v;
            if (row < Nc) s_hb[row * ROWP + col] = f2bf(v);
        }
    // ---- adjacency scan (streaming, non-temporal) ----
    for (int p = tid; p < Nc * Nc; p += T) {
        const fvec4* e4 = (const fvec4*)(edges_b + p * FEc);
        fvec4 a0 = __builtin_nontemporal_load(e4);
        fvec4 a1 = __builtin_nontemporal_load(e4 + 1);
        fvec4 a2 = __builtin_nontemporal_load(e4 + 2);
        fvec4 a3 = __builtin_nontemporal_load(e4 + 3);
        float s = a0.x + a0.y + a0.z + a0.w + a1.x + a1.y + a1.z + a1.w
                + a2.x + a2.y + a2.z + a2.w + a3.x + a3.y + a3.z + a3.w;
        ((unsigned char*)s_nbr)[p] = (s > 0.f) ? 1 : 0;
    }
    __syncthreads();
    if (tid < Nc) {               // compact neighbor list in place
        int c = 0;
#pragma unroll 1
        for (int j = 0; j < Nc; ++j)
            if (s_nbr[tid][j]) { s_nbr[tid][c] = (unsigned char)j; ++c; }
        s_cnt[tid] = c;
    }
    __syncthreads();
    if (tid == 0) {
        int tot = 0;
#pragma unroll 1
        for (int i = 0; i < Nc; ++i) { s_off[i] = tot; tot += s_cnt[i]; }
        s_total = tot;
    }
    __syncthreads();
    int* slot_src = (int*)s_eb;   // temp alias; dead before pass-0 Phase A writes s_eb
    if (tid < Nc) {
        int base = s_off[tid], cnt = s_cnt[tid];
#pragma unroll 1
        for (int kn = 0; kn < cnt; ++kn) {
            int slot = base + kn;
            if (slot < EPOOL) slot_src[slot] = tid * Nc + s_nbr[tid][kn];
        }
    }
    __syncthreads();
    const int E = s_total < EPOOL ? s_total : EPOOL;
    {   // fill compact bf16 edge pool; zero tail (clean MFMA inputs)
#pragma unroll 1
        for (int w = tid; w < EPOOL * 2; w += T) {
            int s = w >> 1, hf = w & 1;
            short8 v = {0,0,0,0,0,0,0,0};
            if (s < E) {
                const float* src = edges_b + (size_t)slot_src[s] * FEc + hf * 8;
                fvec4 x = __builtin_nontemporal_load((const fvec4*)src);
                fvec4 y = __builtin_nontemporal_load((const fvec4*)(src + 4));
                v[0] = (short)f2bf(x.x); v[1] = (short)f2bf(x.y); v[2] = (short)f2bf(x.z); v[3] = (short)f2bf(x.w);
                v[4] = (short)f2bf(y.x); v[5] = (short)f2bf(y.y); v[6] = (short)f2bf(y.z); v[7] = (short)f2bf(y.w);
            }
            *(short8*)(s_pool + s * FEc + hf * 8) = v;
        }
    }
    __syncthreads();

    if constexpr (USE_EP) {   // ep = edges@We (pass-invariant) via MFMA -> global ws
        int nT = (E + 15) >> 4;
#pragma unroll 1
        for (int st = wave; st < nT; st += 8) {
            short8 a = {0,0,0,0,0,0,0,0};
            if (quad < 2)
                a = *(const short8*)(s_pool + (st * 16 + l16) * FEc + quad * 8);
#pragma unroll
            for (int ne = 0; ne < 8; ++ne) {
                floatx4 acc = {0.f, 0.f, 0.f, 0.f};
                acc = mm(a, bfrag(ws + WS_WE16, ne, 1, 0, lane), acc);
#pragma unroll
                for (int reg = 0; reg < 4; ++reg) {
                    int slot = st * 16 + quad * 4 + reg;
                    if (slot < EPOOL) epb[slot * Mc + ne * 16 + l16] = f2bf(acc[reg]);
                }
            }
        }
        __syncthreads();
    }

    for (int pass = 0; pass < NPASS; ++pass) {
        // ---- Phase A: np = h@Wn, emb = h@Wm; wave nt does both jb for its nt ----
#pragma unroll
        for (int jb = 0; jb < 2; ++jb) {
            const unsigned short* wb = jb ? wWm : wWn;
            unsigned short* dst = jb ? s_eb : s_npb;
#pragma unroll
            for (int mt = 0; mt < 3; ++mt) {
                floatx4 acc = {0.f, 0.f, 0.f, 0.f};
#pragma unroll
                for (int kt = 0; kt < 4; ++kt)
                    acc = mm(afrag(s_hb, mt, kt, lane), bfrag(wb, wave, 4, kt, lane), acc);
#pragma unroll
                for (int reg = 0; reg < 4; ++reg) {
                    int row = mt * 16 + quad * 4 + reg;
                    if (row < Nc) dst[row * ROWP + col] = f2bf(acc[reg]);
                }
            }
        }
        __syncthreads();

        // ---- Attention: 4 groups x 10 rows; 4-wide unroll -> 4 outstanding ep loads ----
#pragma unroll 1
        for (int ib = 0; ib < 10; ++ib) {
            int i = g + ib * 4;
            int cnt = s_cnt[i], base = s_off[i];
            int cap = EPOOL - base; if (cap > cnt) cap = cnt; if (cap < 0) cap = 0;
            float pd0 = 0.f, pd1 = 0.f, pd2 = 0.f, pd3 = 0.f;
            float pn0 = 0.f, pn1 = 0.f, pn2 = 0.f, pn3 = 0.f;
            int kn = 0;
            if constexpr (USE_EP) {
#pragma unroll 1
                for (; kn + 4 <= cap; kn += 4) {
                    int j0 = s_nbr[i][kn], j1 = s_nbr[i][kn+1], j2 = s_nbr[i][kn+2], j3 = s_nbr[i][kn+3];
                    float e0 = bf2f(epb[(base+kn  ) * Mc + m]);
                    float e1 = bf2f(epb[(base+kn+1) * Mc + m]);
                    float e2 = bf2f(epb[(base+kn+2) * Mc + m]);
                    float e3 = bf2f(epb[(base+kn+3) * Mc + m]);
                    float w0 = __expf(fast_tanh(e0 + bf2f(s_npb[j0*ROWP+m])));
                    float w1 = __expf(fast_tanh(e1 + bf2f(s_npb[j1*ROWP+m])));
                    float w2 = __expf(fast_tanh(e2 + bf2f(s_npb[j2*ROWP+m])));
                    float w3 = __expf(fast_tanh(e3 + bf2f(s_npb[j3*ROWP+m])));
                    pd0 += w0; pn0 += w0 * bf2f(s_eb[j0*ROWP+m]);
                    pd1 += w1; pn1 += w1 * bf2f(s_eb[j1*ROWP+m]);
                    pd2 += w2; pn2 += w2 * bf2f(s_eb[j2*ROWP+m]);
                    pd3 += w3; pn3 += w3 * bf2f(s_eb[j3*ROWP+m]);
                }
#pragma unroll 1
                for (; kn < cap; ++kn) {
                    int j = s_nbr[i][kn];
                    float w = __expf(fast_tanh(bf2f(epb[(base+kn)*Mc+m]) + bf2f(s_npb[j*ROWP+m])));
                    pd0 += w; pn0 += w * bf2f(s_eb[j*ROWP+m]);
                }
            } else {   // no-ep variant: bf16 pool dot product
                float wef[FEc];
#pragma unroll
                for (int f = 0; f < FEc; ++f) wef[f] = We[f * Mc + m];
#pragma unroll 1
                for (; kn < cap; ++kn) {
                    int j = s_nbr[i][kn];
                    const unsigned int* e = (const unsigned int*)(s_pool + (base+kn) * FEc);
                    uint4 p0 = *(const uint4*)e;
                    uint4 p1 = *(const uint4*)(e + 4);
                    float ep = bflo(p0.x)*wef[0]  + bfhi(p0.x)*wef[1]
                             + bflo(p0.y)*wef[2]  + bfhi(p0.y)*wef[3]
                             + bflo(p0.z)*wef[4]  + bfhi(p0.z)*wef[5]
                             + bflo(p0.w)*wef[6]  + bfhi(p0.w)*wef[7]
                             + bflo(p1.x)*wef[8]  + bfhi(p1.x)*wef[9]
                             + bflo(p1.y)*wef[10] + bfhi(p1.y)*wef[11]
                             + bflo(p1.z)*wef[12] + bfhi(p1.z)*wef[13]
                             + bflo(p1.w)*wef[14] + bfhi(p1.w)*wef[15];
                    float w = __expf(fast_tanh(ep + bf2f(s_npb[j*ROWP+m])));
                    pd0 += w; pn0 += w * bf2f(s_eb[j*ROWP+m]);
                }
            }
#pragma unroll 1
            for (; kn < cnt; ++kn) {   // pool-overflow tail (statistically never)
                int j = s_nbr[i][kn];
                const float4* ef = (const float4*)(edges_b + ((size_t)i * Nc + j) * FEc);
                float4 a0 = ef[0], a1 = ef[1], a2 = ef[2], a3 = ef[3];
                float ep = a0.x*We[0*Mc+m] + a0.y*We[1*Mc+m] + a0.z*We[2*Mc+m] + a0.w*We[3*Mc+m]
                         + a1.x*We[4*Mc+m] + a1.y*We[5*Mc+m] + a1.z*We[6*Mc+m] + a1.w*We[7*Mc+m]
                         + a2.x*We[8*Mc+m] + a2.y*We[9*Mc+m] + a2.z*We[10*Mc+m]+ a2.w*We[11*Mc+m]
                         + a3.x*We[12*Mc+m]+ a3.y*We[13*Mc+m]+ a3.z*We[14*Mc+m]+ a3.w*We[15*Mc+m];
                float w = __expf(fast_tanh(ep + bf2f(s_npb[j*ROWP+m])));
                pd0 += w; pn0 += w * bf2f(s_eb[j*ROWP+m]);
            }
            float pden = (pd0 + pd1) + (pd2 + pd3);
            float pnum = (pn0 + pn1) + (pn2 + pn3);
            s_mb[i * ROWP + m] = f2bf((cnt > 0) ? pnum * fast_rcp(pden) : 0.f);
        }
        __syncthreads();

        // ---- GRU alpha: r,z (one acc live at a time; same-thread r/z reuse in beta) ----
#pragma unroll
        for (int grp = 0; grp < 2; ++grp) {
            unsigned short* dst = grp ? s_eb : s_npb;   // np/emb dead after attention
            float bb = bi[grp * 128 + col] + bh[grp * 128 + col];
#pragma unroll
            for (int mt = 0; mt < 3; ++mt) {
                floatx4 acc = {0.f,0.f,0.f,0.f};
#pragma unroll
                for (int kt = 0; kt < 4; ++kt) {
                    acc = mm(afrag(s_mb, mt, kt, lane), bfrag(wWi, grp * 8 + wave, 4, kt, lane), acc);
                    acc = mm(afrag(s_hb, mt, kt, lane), bfrag(wWh, grp * 8 + wave, 4, kt, lane), acc);
                }
#pragma unroll
                for (int reg = 0; reg < 4; ++reg) {
                    int row = mt * 16 + quad * 4 + reg;
                    if (row < Nc) dst[row * ROWP + col] = f2bf(fast_sigmoid(acc[reg] + bb));
                }
            }
        }
        // ---- GRU beta: candidate + h update (r/z written by same thread; no barrier) ----
        float hn[3][4];
        {
            float bnI = bi[256 + col], bnH = bh[256 + col];
#pragma unroll
            for (int mt = 0; mt < 3; ++mt) {
                floatx4 ai = {0.f,0.f,0.f,0.f}, ah = {0.f,0.f,0.f,0.f};
#pragma unroll
                for (int kt = 0; kt < 4; ++kt) {
                    ai = mm(afrag(s_mb, mt, kt, lane), bfrag(wWi, 16 + wave, 4, kt, lane), ai);
                    ah = mm(afrag(s_hb, mt, kt, lane), bfrag(wWh, 16 + wave, 4, kt, lane), ah);
                }
#pragma unroll
                for (int reg = 0; reg < 4; ++reg) {
                    int row = mt * 16 + quad * 4 + reg;
                    float hold = hreg[mt][reg];
                    if (row < Nc) {
                        float r = bf2f(s_npb[row * ROWP + col]);
                        float z = bf2f(s_eb[row * ROWP + col]);
                        float n = fast_tanh(ai[reg] + bnI + r * (ah[reg] + bnH));
                        float v = (1.f - z) * n + z * hold;
                        hn[mt][reg] = (s_cnt[row] > 0) ? v : hold;
                    } else hn[mt][reg] = hold;
                }
            }
        }
        __syncthreads();   // all afrag reads of s_hb done before overwrite
#pragma unroll
        for (int mt = 0; mt < 3; ++mt)
#pragma unroll
            for (int reg = 0; reg < 4; ++reg) {
                int row = mt * 16 + quad * 4 + reg;
                hreg[mt][reg] = hn[mt][reg];
                if (row < Nc) s_hb[row * ROWP + col] = f2bf(hn[mt][reg]);
            }
        __syncthreads();
    }

    // ---- Readout ----
    for (int idx = tid; idx < Nc * Hc; idx += T) {
        int row = idx >> 7, c2 = idx & 127;
        s_mb[row * ROWP + c2] = f2bf(nodes_b[idx]);   // cat tail
    }
    __syncthreads();
    float psum = 0.f;
    {
        float bgv = bg[col], bov = bo[col];
#pragma unroll
        for (int mt = 0; mt < 3; ++mt) {
            floatx4 ga = {0.f,0.f,0.f,0.f}, oa = {0.f,0.f,0.f,0.f};
#pragma unroll
            for (int kt = 0; kt < 8; ++kt) {
                short8 a = (kt < 4) ? afrag(s_hb, mt, kt, lane) : afrag(s_mb, mt, kt - 4, lane);
                ga = mm(a, bfrag(wWg, wave, 8, kt, lane), ga);
                oa = mm(a, bfrag(wWo, wave, 8, kt, lane), oa);
            }
#pragma unroll
            for (int reg = 0; reg < 4; ++reg) {
                int row = mt * 16 + quad * 4 + reg;
                if (row < Nc && s_cnt[row] > 0)
                    psum += fast_sigmoid(ga[reg] + bgv) * (oa[reg] + bov);
            }
        }
    }
    psum += __shfl_xor(psum, 16);   // reduce the 4 quads sharing this col
    psum += __shfl_xor(psum, 32);
    if (quad == 0) out[(size_t)b * OUTc + col] = psum;
}

extern "C" void kernel_launch(void* const* d_in, const int* in_sizes, int n_in,
                              void* d_out, int out_size, void* d_ws, size_t ws_size,
                              hipStream_t stream) {
    const float* nodes = (const float*)d_in[0];
    const float* edges = (const float*)d_in[1];
    const float* We = (const float*)d_in[2];
    const float* Wn = (const float*)d_in[3];
    const float* Wm = (const float*)d_in[4];
    const float* Wi = (const float*)d_in[5];
    const float* Wh = (const float*)d_in[6];
    const float* bi = (const float*)d_in[7];
    const float* bh = (const float*)d_in[8];
    const float* Wg = (const float*)d_in[9];
    const float* bg = (const float*)d_in[10];
    const float* Wo = (const float*)d_in[11];
    const float* bo = (const float*)d_in[12];
    float* out = (float*)d_out;
    unsigned short* ws = (unsigned short*)d_ws;

    size_t need = ((size_t)WS_EP + (size_t)Bc * EPOOL * Mc) * sizeof(unsigned short);

    prep_kernel<<<392, 64, 0, stream>>>(Wn, Wm, Wi, Wh, Wg, Wo, We, ws);
    if (ws_size >= need)
        mpnn_kernel<true><<<Bc, T, 0, stream>>>(nodes, edges, We, bi, bh, bg, bo,
                                                ws, ws + WS_EP, out);
    else
        mpnn_kernel<false><<<Bc, T, 0, stream>>>(nodes, edges, We, bi, bh, bg, bo,
                                                 ws, ws, out);
}

// Round 8
// 469.230 us; speedup vs baseline: 1.0776x; 1.0776x over previous
//
#include <hip/hip_runtime.h>

#define T 512
constexpr int Bc = 512, Nc = 40, Hc = 128, FEc = 16, Mc = 128, OUTc = 128, NPASS = 3;
constexpr int ROWP = 136;   // bf16 LDS row pitch
constexpr int HP   = 132;   // fp32 LDS row pitch
constexpr int EPOOL = 512;  // ep slots per block (mean ~296, sigma ~22; fallback covers overflow)

typedef __attribute__((ext_vector_type(8))) short short8;
typedef __attribute__((ext_vector_type(4))) float floatx4;
typedef __attribute__((ext_vector_type(4))) float fvec4;

// ws layout (bf16 elements): fragment-major B operands, K-padded We, then per-block ep
constexpr int WS_WN = 0, WS_WM = 16384, WS_WI = 32768, WS_WH = 81920, WS_WG = 131072, WS_WO = 163840;
constexpr int WS_WE16 = 196608;           // We padded to K=32
constexpr int WS_EP   = 200704;           // ep: Bc * EPOOL * 128 bf16

__device__ __forceinline__ float fast_rcp(float x) { return __builtin_amdgcn_rcpf(x); }
__device__ __forceinline__ float fast_sigmoid(float x) { return fast_rcp(1.f + __expf(-x)); }
__device__ __forceinline__ float fast_tanh(float x) {
    float t = __expf(2.f * x);
    return 1.f - 2.f * fast_rcp(t + 1.f);
}
__device__ __forceinline__ float bf2f(unsigned short u) {
    union { unsigned int i; float f; } v; v.i = ((unsigned int)u) << 16; return v.f;
}
__device__ __forceinline__ unsigned short f2bf(float f) {
    union { float f; unsigned int i; } v; v.f = f;
    unsigned int r = v.i + 0x7fff + ((v.i >> 16) & 1);   // RNE
    return (unsigned short)(r >> 16);
}

__device__ __forceinline__ floatx4 mm(short8 a, short8 b, floatx4 c) {
    return __builtin_amdgcn_mfma_f32_16x16x32_bf16(a, b, c, 0, 0, 0);
}
// A-fragment: A[m=lane&15][k=quad*8+j]; rows>=40 clamped (their C rows discarded)
__device__ __forceinline__ short8 afrag(const unsigned short* buf, int mt, int kt, int lane) {
    int row = mt * 16 + (lane & 15); row = row > 39 ? 39 : row;
    return *(const short8*)(buf + row * ROWP + kt * 32 + (lane >> 4) * 8);
}
__device__ __forceinline__ short8 bfrag(const unsigned short* w, int nt, int nKT, int kt, int lane) {
    return *(const short8*)(w + ((nt * nKT + kt) * 64 + lane) * 8);
}

// ---- prep: weights -> bf16 B-fragment layout in ws ----
__global__ void prep_kernel(const float* __restrict__ Wn, const float* __restrict__ Wm,
                            const float* __restrict__ Wi, const float* __restrict__ Wh,
                            const float* __restrict__ Wg, const float* __restrict__ Wo,
                            const float* __restrict__ We, unsigned short* __restrict__ ws) {
    int c = blockIdx.x, lane = threadIdx.x;
    int quad = lane >> 4, l16 = lane & 15;
    if (c >= 384) {          // We padded to K=32 (rows 16..31 zero)
        int nt = c - 384;
        short8 v;
#pragma unroll
        for (int j = 0; j < 8; ++j) {
            int k = quad * 8 + j;
            v[j] = (k < FEc) ? (short)f2bf(We[k * Mc + nt * 16 + l16]) : (short)0;
        }
        *(short8*)(ws + WS_WE16 + nt * 512 + lane * 8) = v;
        return;
    }
    const float* W; int N, nKT, local; unsigned short* dst;
    if (c < 32)       { W = Wn; N = 128; nKT = 4; local = c;       dst = ws + WS_WN; }
    else if (c < 64)  { W = Wm; N = 128; nKT = 4; local = c - 32;  dst = ws + WS_WM; }
    else if (c < 160) { W = Wi; N = 384; nKT = 4; local = c - 64;  dst = ws + WS_WI; }
    else if (c < 256) { W = Wh; N = 384; nKT = 4; local = c - 160; dst = ws + WS_WH; }
    else if (c < 320) { W = Wg; N = 128; nKT = 8; local = c - 256; dst = ws + WS_WG; }
    else              { W = Wo; N = 128; nKT = 8; local = c - 320; dst = ws + WS_WO; }
    int nt = local / nKT, kt = local % nKT;
    short8 v;
#pragma unroll
    for (int j = 0; j < 8; ++j) {
        int k = kt * 32 + quad * 8 + j;
        v[j] = (short)f2bf(W[k * N + nt * 16 + l16]);
    }
    *(short8*)(dst + local * 512 + lane * 8) = v;
}

// T=512, 8 waves, LDS ~67 KB -> 2 blocks/CU. Minimal per-thread live state (R6 lesson):
// h fp32 in LDS (1:1 thread-owned), one MFMA acc set at a time, r/z via LDS.
template<bool USE_EP>
__global__ __launch_bounds__(T, 4) void mpnn_kernel(
    const float* __restrict__ nodes, const float* __restrict__ edges,
    const float* __restrict__ We, const float* __restrict__ bi,
    const float* __restrict__ bh, const float* __restrict__ bg,
    const float* __restrict__ bo, const unsigned short* __restrict__ ws,
    unsigned short* __restrict__ ep_g,
    float* __restrict__ out)
{
    __shared__ __attribute__((aligned(16))) unsigned short s_hb[Nc * ROWP];   // bf16 h
    __shared__ __attribute__((aligned(16))) unsigned short s_mb[Nc * ROWP];   // messages / nodes(cat)
    __shared__ __attribute__((aligned(16))) unsigned short s_npb[Nc * ROWP];  // np, then r-gate
    __shared__ __attribute__((aligned(16))) unsigned short s_eb[Nc * ROWP];   // emb, then z (init: slot_src)
    __shared__ float s_hf[Nc * HP];                                           // fp32 h (thread-owned r/w)
    __shared__ unsigned char s_nbr[Nc][Nc];
    __shared__ int s_cnt[Nc];
    __shared__ int s_off[Nc];
    __shared__ int s_total;

    const int b = blockIdx.x, tid = threadIdx.x;
    const int lane = tid & 63, wave = tid >> 6;          // 8 waves; nt = wave
    const int quad = lane >> 4, l16 = lane & 15;
    const int m = tid & 127, g = tid >> 7;               // attention: g in 0..3
    const int col = wave * 16 + l16;

    const float* nodes_b = nodes + (size_t)b * Nc * Hc;
    const float* edges_b = edges + (size_t)b * Nc * Nc * FEc;
    const unsigned short* wWn = ws + WS_WN; const unsigned short* wWm = ws + WS_WM;
    const unsigned short* wWi = ws + WS_WI; const unsigned short* wWh = ws + WS_WH;
    const unsigned short* wWg = ws + WS_WG; const unsigned short* wWo = ws + WS_WO;
    unsigned short* epb = ep_g + (size_t)b * EPOOL * Mc;

    // ---- init h (fp32 + bf16, both LDS) ----
    for (int idx = tid; idx < Nc * Hc; idx += T) {
        int row = idx >> 7, c2 = idx & 127;
        float v = nodes_b[idx];
        s_hf[row * HP + c2] = v;
        s_hb[row * ROWP + c2] = f2bf(v);
    }
    // ---- adjacency scan (streaming, non-temporal) ----
    for (int p = tid; p < Nc * Nc; p += T) {
        const fvec4* e4 = (const fvec4*)(edges_b + p * FEc);
        fvec4 a0 = __builtin_nontemporal_load(e4);
        fvec4 a1 = __builtin_nontemporal_load(e4 + 1);
        fvec4 a2 = __builtin_nontemporal_load(e4 + 2);
        fvec4 a3 = __builtin_nontemporal_load(e4 + 3);
        float s = a0.x + a0.y + a0.z + a0.w + a1.x + a1.y + a1.z + a1.w
                + a2.x + a2.y + a2.z + a2.w + a3.x + a3.y + a3.z + a3.w;
        ((unsigned char*)s_nbr)[p] = (s > 0.f) ? 1 : 0;
    }
    __syncthreads();
    if (tid < Nc) {               // compact neighbor list in place
        int c = 0;
#pragma unroll 1
        for (int j = 0; j < Nc; ++j)
            if (s_nbr[tid][j]) { s_nbr[tid][c] = (unsigned char)j; ++c; }
        s_cnt[tid] = c;
    }
    __syncthreads();
    if (tid == 0) {
        int tot = 0;
#pragma unroll 1
        for (int i = 0; i < Nc; ++i) { s_off[i] = tot; tot += s_cnt[i]; }
        s_total = tot;
    }
    __syncthreads();

    if constexpr (USE_EP) {
        int* slot_src = (int*)s_eb;   // temp alias; dead before pass-0 Phase A writes s_eb
        if (tid < Nc) {
            int base = s_off[tid], cnt = s_cnt[tid];
#pragma unroll 1
            for (int kn = 0; kn < cnt; ++kn) {
                int slot = base + kn;
                if (slot < EPOOL) slot_src[slot] = tid * Nc + s_nbr[tid][kn];
            }
        }
        __syncthreads();
        // ep = edges@We (pass-invariant) via MFMA, edges loaded straight from global
        const int E = s_total < EPOOL ? s_total : EPOOL;
        int nT = (E + 15) >> 4;
#pragma unroll 1
        for (int st = wave; st < nT; st += 8) {
            short8 a = {0,0,0,0,0,0,0,0};
            int slot = st * 16 + l16;
            if (quad < 2 && slot < E) {   // K = quad*8+j < 16; upper K zero (We rows padded)
                const float* src = edges_b + (size_t)slot_src[slot] * FEc + quad * 8;
                fvec4 x = __builtin_nontemporal_load((const fvec4*)src);
                fvec4 y = __builtin_nontemporal_load((const fvec4*)(src + 4));
                a[0] = (short)f2bf(x.x); a[1] = (short)f2bf(x.y); a[2] = (short)f2bf(x.z); a[3] = (short)f2bf(x.w);
                a[4] = (short)f2bf(y.x); a[5] = (short)f2bf(y.y); a[6] = (short)f2bf(y.z); a[7] = (short)f2bf(y.w);
            }
#pragma unroll
            for (int ne = 0; ne < 8; ++ne) {
                floatx4 acc = {0.f, 0.f, 0.f, 0.f};
                acc = mm(a, bfrag(ws + WS_WE16, ne, 1, 0, lane), acc);
#pragma unroll
                for (int reg = 0; reg < 4; ++reg) {
                    int s2 = st * 16 + quad * 4 + reg;
                    if (s2 < EPOOL) epb[s2 * Mc + ne * 16 + l16] = f2bf(acc[reg]);
                }
            }
        }
        __syncthreads();
    }

    for (int pass = 0; pass < NPASS; ++pass) {
        // ---- Phase A: np = h@Wn, emb = h@Wm; wave handles its nt for both ----
#pragma unroll
        for (int jb = 0; jb < 2; ++jb) {
            const unsigned short* wb = jb ? wWm : wWn;
            unsigned short* dst = jb ? s_eb : s_npb;
#pragma unroll
            for (int mt = 0; mt < 3; ++mt) {
                floatx4 acc = {0.f, 0.f, 0.f, 0.f};
#pragma unroll
                for (int kt = 0; kt < 4; ++kt)
                    acc = mm(afrag(s_hb, mt, kt, lane), bfrag(wb, wave, 4, kt, lane), acc);
#pragma unroll
                for (int reg = 0; reg < 4; ++reg) {
                    int row = mt * 16 + quad * 4 + reg;
                    if (row < Nc) dst[row * ROWP + col] = f2bf(acc[reg]);
                }
            }
        }
        __syncthreads();

        // ---- Attention: 4 groups x 10 rows; 2-wide unroll (ILP without spill) ----
#pragma unroll 1
        for (int ib = 0; ib < 10; ++ib) {
            int i = g + ib * 4;
            int cnt = s_cnt[i], base = s_off[i];
            float pd0 = 0.f, pd1 = 0.f, pn0 = 0.f, pn1 = 0.f;
            int kn = 0;
            if constexpr (USE_EP) {
                int cap = EPOOL - base; if (cap > cnt) cap = cnt; if (cap < 0) cap = 0;
#pragma unroll 1
                for (; kn + 2 <= cap; kn += 2) {
                    int j0 = s_nbr[i][kn], j1 = s_nbr[i][kn + 1];
                    float e0 = bf2f(epb[(base + kn    ) * Mc + m]);
                    float e1 = bf2f(epb[(base + kn + 1) * Mc + m]);
                    float w0 = __expf(fast_tanh(e0 + bf2f(s_npb[j0 * ROWP + m])));
                    float w1 = __expf(fast_tanh(e1 + bf2f(s_npb[j1 * ROWP + m])));
                    pd0 += w0; pn0 += w0 * bf2f(s_eb[j0 * ROWP + m]);
                    pd1 += w1; pn1 += w1 * bf2f(s_eb[j1 * ROWP + m]);
                }
#pragma unroll 1
                for (; kn < cap; ++kn) {
                    int j = s_nbr[i][kn];
                    float w = __expf(fast_tanh(bf2f(epb[(base + kn) * Mc + m]) + bf2f(s_npb[j * ROWP + m])));
                    pd0 += w; pn0 += w * bf2f(s_eb[j * ROWP + m]);
                }
            }
#pragma unroll 1
            for (; kn < cnt; ++kn) {   // overflow / no-ep path: fp32 global dot
                int j = s_nbr[i][kn];
                const float4* ef = (const float4*)(edges_b + ((size_t)i * Nc + j) * FEc);
                float4 a0 = ef[0], a1 = ef[1], a2 = ef[2], a3 = ef[3];
                float ep = a0.x*We[0*Mc+m] + a0.y*We[1*Mc+m] + a0.z*We[2*Mc+m] + a0.w*We[3*Mc+m]
                         + a1.x*We[4*Mc+m] + a1.y*We[5*Mc+m] + a1.z*We[6*Mc+m] + a1.w*We[7*Mc+m]
                         + a2.x*We[8*Mc+m] + a2.y*We[9*Mc+m] + a2.z*We[10*Mc+m]+ a2.w*We[11*Mc+m]
                         + a3.x*We[12*Mc+m]+ a3.y*We[13*Mc+m]+ a3.z*We[14*Mc+m]+ a3.w*We[15*Mc+m];
                float w = __expf(fast_tanh(ep + bf2f(s_npb[j * ROWP + m])));
                pd0 += w; pn0 += w * bf2f(s_eb[j * ROWP + m]);
            }
            float pden = pd0 + pd1, pnum = pn0 + pn1;
            s_mb[i * ROWP + m] = f2bf((cnt > 0) ? pnum * fast_rcp(pden) : 0.f);
        }
        __syncthreads();

        // ---- GRU alpha: r,z gates (one acc set live; same-thread handoff to beta) ----
#pragma unroll
        for (int grp = 0; grp < 2; ++grp) {
            unsigned short* dst = grp ? s_eb : s_npb;   // np/emb dead after attention
            float bb = bi[grp * 128 + col] + bh[grp * 128 + col];
#pragma unroll
            for (int mt = 0; mt < 3; ++mt) {
                floatx4 acc = {0.f,0.f,0.f,0.f};
#pragma unroll
                for (int kt = 0; kt < 4; ++kt) {
                    acc = mm(afrag(s_mb, mt, kt, lane), bfrag(wWi, grp * 8 + wave, 4, kt, lane), acc);
                    acc = mm(afrag(s_hb, mt, kt, lane), bfrag(wWh, grp * 8 + wave, 4, kt, lane), acc);
                }
#pragma unroll
                for (int reg = 0; reg < 4; ++reg) {
                    int row = mt * 16 + quad * 4 + reg;
                    if (row < Nc) dst[row * ROWP + col] = f2bf(fast_sigmoid(acc[reg] + bb));
                }
            }
        }
        // ---- GRU beta: candidate + h_new (r/z same-thread; hold from LDS) ----
        float hn[3][4];
        {
            float bnI = bi[256 + col], bnH = bh[256 + col];
#pragma unroll
            for (int mt = 0; mt < 3; ++mt) {
                floatx4 ai = {0.f,0.f,0.f,0.f}, ah = {0.f,0.f,0.f,0.f};
#pragma unroll
                for (int kt = 0; kt < 4; ++kt) {
                    ai = mm(afrag(s_mb, mt, kt, lane), bfrag(wWi, 16 + wave, 4, kt, lane), ai);
                    ah = mm(afrag(s_hb, mt, kt, lane), bfrag(wWh, 16 + wave, 4, kt, lane), ah);
                }
#pragma unroll
                for (int reg = 0; reg < 4; ++reg) {
                    int row = mt * 16 + quad * 4 + reg;
                    if (row < Nc) {
                        float hold = s_hf[row * HP + col];
                        float r = bf2f(s_npb[row * ROWP + col]);
                        float z = bf2f(s_eb[row * ROWP + col]);
                        float n = fast_tanh(ai[reg] + bnI + r * (ah[reg] + bnH));
                        float v = (1.f - z) * n + z * hold;
                        hn[mt][reg] = (s_cnt[row] > 0) ? v : hold;
                    } else hn[mt][reg] = 0.f;
                }
            }
        }
        __syncthreads();   // all afrag reads of s_hb done before overwrite
#pragma unroll
        for (int mt = 0; mt < 3; ++mt)
#pragma unroll
            for (int reg = 0; reg < 4; ++reg) {
                int row = mt * 16 + quad * 4 + reg;
                if (row < Nc) {
                    s_hf[row * HP + col] = hn[mt][reg];
                    s_hb[row * ROWP + col] = f2bf(hn[mt][reg]);
                }
            }
        __syncthreads();
    }

    // ---- Readout ----
    for (int idx = tid; idx < Nc * Hc; idx += T) {
        int row = idx >> 7, c2 = idx & 127;
        s_mb[row * ROWP + c2] = f2bf(nodes_b[idx]);   // cat tail (messages dead)
    }
    __syncthreads();
    float psum = 0.f;
    {
        float bgv = bg[col], bov = bo[col];
#pragma unroll
        for (int mt = 0; mt < 3; ++mt) {
            floatx4 ga = {0.f,0.f,0.f,0.f}, oa = {0.f,0.f,0.f,0.f};
#pragma unroll
            for (int kt = 0; kt < 8; ++kt) {
                short8 a = (kt < 4) ? afrag(s_hb, mt, kt, lane) : afrag(s_mb, mt, kt - 4, lane);
                ga = mm(a, bfrag(wWg, wave, 8, kt, lane), ga);
                oa = mm(a, bfrag(wWo, wave, 8, kt, lane), oa);
            }
#pragma unroll
            for (int reg = 0; reg < 4; ++reg) {
                int row = mt * 16 + quad * 4 + reg;
                if (row < Nc && s_cnt[row] > 0)
                    psum += fast_sigmoid(ga[reg] + bgv) * (oa[reg] + bov);
            }
        }
    }
    psum += __shfl_xor(psum, 16);   // reduce the 4 quads sharing this col
    psum += __shfl_xor(psum, 32);
    if (quad == 0) out[(size_t)b * OUTc + col] = psum;
}

extern "C" void kernel_launch(void* const* d_in, const int* in_sizes, int n_in,
                              void* d_out, int out_size, void* d_ws, size_t ws_size,
                              hipStream_t stream) {
    const float* nodes = (const float*)d_in[0];
    const float* edges = (const float*)d_in[1];
    const float* We = (const float*)d_in[2];
    const float* Wn = (const float*)d_in[3];
    const float* Wm = (const float*)d_in[4];
    const float* Wi = (const float*)d_in[5];
    const float* Wh = (const float*)d_in[6];
    const float* bi = (const float*)d_in[7];
    const float* bh = (const float*)d_in[8];
    const float* Wg = (const float*)d_in[9];
    const float* bg = (const float*)d_in[10];
    const float* Wo = (const float*)d_in[11];
    const float* bo = (const float*)d_in[12];
    float* out = (float*)d_out;
    unsigned short* ws = (unsigned short*)d_ws;

    size_t need = ((size_t)WS_EP + (size_t)Bc * EPOOL * Mc) * sizeof(unsigned short);

    prep_kernel<<<392, 64, 0, stream>>>(Wn, Wm, Wi, Wh, Wg, Wo, We, ws);
    if (ws_size >= need)
        mpnn_kernel<true><<<Bc, T, 0, stream>>>(nodes, edges, We, bi, bh, bg, bo,
                                                ws, ws + WS_EP, out);
    else
        mpnn_kernel<false><<<Bc, T, 0, stream>>>(nodes, edges, We, bi, bh, bg, bo,
                                                 ws, ws, out);
}

// Round 9
// 277.317 us; speedup vs baseline: 1.8234x; 1.6920x over previous
//
#include <hip/hip_runtime.h>

#define T 512
constexpr int Bc = 512, Nc = 40, Hc = 128, FEc = 16, Mc = 128, OUTc = 128, NPASS = 3;
constexpr int ROWP = 136;   // bf16 LDS row pitch (multiple of 8 for aligned b128 reads)
constexpr int EPOOL = 512;  // LDS edge pool slots (mean ~296, sigma ~22; fallback covers overflow)

typedef __attribute__((ext_vector_type(8))) short short8;
typedef __attribute__((ext_vector_type(4))) float floatx4;
typedef __attribute__((ext_vector_type(4))) float fvec4;

// ws layout (bf16 elements): fragment-major B operands only (384 KB, L2-resident)
constexpr int WS_WN = 0, WS_WM = 16384, WS_WI = 32768, WS_WH = 81920, WS_WG = 131072, WS_WO = 163840;

__device__ __forceinline__ float fast_rcp(float x) { return __builtin_amdgcn_rcpf(x); }
__device__ __forceinline__ float fast_sigmoid(float x) { return fast_rcp(1.f + __expf(-x)); }
__device__ __forceinline__ float fast_tanh(float x) {
    float t = __expf(2.f * x);
    return 1.f - 2.f * fast_rcp(t + 1.f);
}
__device__ __forceinline__ float bf2f(unsigned short u) {
    union { unsigned int i; float f; } v; v.i = ((unsigned int)u) << 16; return v.f;
}
__device__ __forceinline__ unsigned short f2bf(float f) {
    union { float f; unsigned int i; } v; v.f = f;
    unsigned int r = v.i + 0x7fff + ((v.i >> 16) & 1);   // RNE
    return (unsigned short)(r >> 16);
}
__device__ __forceinline__ float bflo(unsigned int d) {
    union { unsigned int i; float f; } v; v.i = d << 16; return v.f;
}
__device__ __forceinline__ float bfhi(unsigned int d) {
    union { unsigned int i; float f; } v; v.i = d & 0xffff0000u; return v.f;
}

__device__ __forceinline__ floatx4 mm(short8 a, short8 b, floatx4 c) {
    return __builtin_amdgcn_mfma_f32_16x16x32_bf16(a, b, c, 0, 0, 0);
}
// A-fragment: A[m=lane&15][k=quad*8+j]; rows>=40 clamped (their C rows discarded)
__device__ __forceinline__ short8 afrag(const unsigned short* buf, int mt, int kt, int lane) {
    int row = mt * 16 + (lane & 15); row = row > 39 ? 39 : row;
    return *(const short8*)(buf + row * ROWP + kt * 32 + (lane >> 4) * 8);
}
__device__ __forceinline__ short8 bfrag(const unsigned short* w, int nt, int nKT, int kt, int lane) {
    return *(const short8*)(w + ((nt * nKT + kt) * 64 + lane) * 8);
}

// ---- prep: weights -> bf16 B-fragment layout in ws ----
__global__ void prep_kernel(const float* __restrict__ Wn, const float* __restrict__ Wm,
                            const float* __restrict__ Wi, const float* __restrict__ Wh,
                            const float* __restrict__ Wg, const float* __restrict__ Wo,
                            unsigned short* __restrict__ ws) {
    int c = blockIdx.x, lane = threadIdx.x;
    int quad = lane >> 4, l16 = lane & 15;
    const float* W; int N, nKT, local; unsigned short* dst;
    if (c < 32)       { W = Wn; N = 128; nKT = 4; local = c;       dst = ws + WS_WN; }
    else if (c < 64)  { W = Wm; N = 128; nKT = 4; local = c - 32;  dst = ws + WS_WM; }
    else if (c < 160) { W = Wi; N = 384; nKT = 4; local = c - 64;  dst = ws + WS_WI; }
    else if (c < 256) { W = Wh; N = 384; nKT = 4; local = c - 160; dst = ws + WS_WH; }
    else if (c < 320) { W = Wg; N = 128; nKT = 8; local = c - 256; dst = ws + WS_WG; }
    else              { W = Wo; N = 128; nKT = 8; local = c - 320; dst = ws + WS_WO; }
    int nt = local / nKT, kt = local % nKT;
    short8 v;
#pragma unroll
    for (int j = 0; j < 8; ++j) {
        int k = kt * 32 + quad * 8 + j;
        v[j] = (short)f2bf(W[k * N + nt * 16 + l16]);
    }
    *(short8*)(dst + local * 512 + lane * 8) = v;
}

// T=512, 8 waves, LDS ~62 KB -> 2 blocks/CU (4 waves/SIMD).
// Anti-spill rules: (1) attention reads LDS pool only; (2) every GEMM mt/kt loop is
// `#pragma unroll 1` so no region holds >2 B-frags in flight; (3) private arrays only
// in fully-unrolled code.
__global__ __launch_bounds__(T, 4) void mpnn_kernel(
    const float* __restrict__ nodes, const float* __restrict__ edges,
    const float* __restrict__ We, const float* __restrict__ bi,
    const float* __restrict__ bh, const float* __restrict__ bg,
    const float* __restrict__ bo, const unsigned short* __restrict__ ws,
    float* __restrict__ out)
{
    __shared__ __attribute__((aligned(16))) unsigned short s_hb[Nc * ROWP];   // bf16 h
    __shared__ __attribute__((aligned(16))) unsigned short s_mb[Nc * ROWP];   // messages / nodes(cat)
    __shared__ __attribute__((aligned(16))) unsigned short s_npb[Nc * ROWP];  // np, then r-gate
    __shared__ __attribute__((aligned(16))) unsigned short s_eb[Nc * ROWP];   // emb, then z (init: slot_src)
    __shared__ __attribute__((aligned(16))) unsigned short s_pool[EPOOL * FEc]; // 16 KB bf16 edge features
    __shared__ unsigned char s_nbr[Nc][Nc];
    __shared__ int s_cnt[Nc];
    __shared__ int s_off[Nc];
    __shared__ int s_total;

    const int b = blockIdx.x, tid = threadIdx.x;
    const int lane = tid & 63, wave = tid >> 6;          // 8 waves; nt = wave
    const int quad = lane >> 4, l16 = lane & 15;
    const int m = tid & 127, g = tid >> 7;               // attention: g in 0..3
    const int col = wave * 16 + l16;

    const float* nodes_b = nodes + (size_t)b * Nc * Hc;
    const float* edges_b = edges + (size_t)b * Nc * Nc * FEc;
    const unsigned short* wWn = ws + WS_WN; const unsigned short* wWm = ws + WS_WM;
    const unsigned short* wWi = ws + WS_WI; const unsigned short* wWh = ws + WS_WH;
    const unsigned short* wWg = ws + WS_WG; const unsigned short* wWo = ws + WS_WO;

    // ---- init: h fp32 in registers (static map, fully unrolled), bf16 in LDS ----
    float hreg[3][4];
#pragma unroll
    for (int mt = 0; mt < 3; ++mt)
#pragma unroll
        for (int reg = 0; reg < 4; ++reg) {
            int row = mt * 16 + quad * 4 + reg;
            float v = (row < Nc) ? nodes_b[row * Hc + col] : 0.f;
            hreg[mt][reg] = v;
            if (row < Nc) s_hb[row * ROWP + col] = f2bf(v);
        }
    // ---- adjacency scan (streaming, non-temporal; 210 MB = HBM floor ~33 us) ----
    for (int p = tid; p < Nc * Nc; p += T) {
        const fvec4* e4 = (const fvec4*)(edges_b + p * FEc);
        fvec4 a0 = __builtin_nontemporal_load(e4);
        fvec4 a1 = __builtin_nontemporal_load(e4 + 1);
        fvec4 a2 = __builtin_nontemporal_load(e4 + 2);
        fvec4 a3 = __builtin_nontemporal_load(e4 + 3);
        float s = a0.x + a0.y + a0.z + a0.w + a1.x + a1.y + a1.z + a1.w
                + a2.x + a2.y + a2.z + a2.w + a3.x + a3.y + a3.z + a3.w;
        ((unsigned char*)s_nbr)[p] = (s > 0.f) ? 1 : 0;
    }
    __syncthreads();
    if (tid < Nc) {               // compact neighbor list in place
        int c = 0;
#pragma unroll 1
        for (int j = 0; j < Nc; ++j)
            if (s_nbr[tid][j]) { s_nbr[tid][c] = (unsigned char)j; ++c; }
        s_cnt[tid] = c;
    }
    __syncthreads();
    if (tid == 0) {
        int tot = 0;
#pragma unroll 1
        for (int i = 0; i < Nc; ++i) { s_off[i] = tot; tot += s_cnt[i]; }
        s_total = tot;
    }
    __syncthreads();
    int* slot_src = (int*)s_eb;   // temp alias; dead before pass-0 Phase A writes s_eb
    if (tid < Nc) {
        int base = s_off[tid], cnt = s_cnt[tid];
#pragma unroll 1
        for (int kn = 0; kn < cnt; ++kn) {
            int slot = base + kn;
            if (slot < EPOOL) slot_src[slot] = tid * Nc + s_nbr[tid][kn];
        }
    }
    __syncthreads();
    {   // fill compact bf16 edge pool (once; reused all 3 passes)
        const int E = s_total < EPOOL ? s_total : EPOOL;
#pragma unroll 1
        for (int w = tid; w < E * 2; w += T) {
            int s = w >> 1, hf = w & 1;
            const float* src = edges_b + (size_t)slot_src[s] * FEc + hf * 8;
            fvec4 x = __builtin_nontemporal_load((const fvec4*)src);
            fvec4 y = __builtin_nontemporal_load((const fvec4*)(src + 4));
            short8 v;
            v[0] = (short)f2bf(x.x); v[1] = (short)f2bf(x.y); v[2] = (short)f2bf(x.z); v[3] = (short)f2bf(x.w);
            v[4] = (short)f2bf(y.x); v[5] = (short)f2bf(y.y); v[6] = (short)f2bf(y.z); v[7] = (short)f2bf(y.w);
            *(short8*)(s_pool + s * FEc + hf * 8) = v;
        }
    }
    __syncthreads();

    for (int pass = 0; pass < NPASS; ++pass) {
        // ---- Phase A: np = h@Wn, emb = h@Wm (bfr cached; mt loop unroll 1) ----
#pragma unroll 1
        for (int jb = 0; jb < 2; ++jb) {
            const unsigned short* wb = jb ? wWm : wWn;
            unsigned short* dst = jb ? s_eb : s_npb;
            short8 bfr[4];
#pragma unroll
            for (int kt = 0; kt < 4; ++kt) bfr[kt] = bfrag(wb, wave, 4, kt, lane);
#pragma unroll 1
            for (int mt = 0; mt < 3; ++mt) {
                floatx4 acc = {0.f, 0.f, 0.f, 0.f};
#pragma unroll
                for (int kt = 0; kt < 4; ++kt) acc = mm(afrag(s_hb, mt, kt, lane), bfr[kt], acc);
#pragma unroll
                for (int reg = 0; reg < 4; ++reg) {
                    int row = mt * 16 + quad * 4 + reg;
                    if (row < Nc) dst[row * ROWP + col] = f2bf(acc[reg]);
                }
            }
        }
        __syncthreads();

        // ---- Attention from LDS pool (R4-proven): ~40 VALU/edge, all-LDS latency ----
        {
            float wef[FEc];
#pragma unroll
            for (int f = 0; f < FEc; ++f) wef[f] = We[f * Mc + m];
#pragma unroll 1
            for (int ib = 0; ib < 10; ++ib) {
                int i = g + ib * 4;
                int cnt = s_cnt[i], base = s_off[i];
                int cap = EPOOL - base; if (cap > cnt) cap = cnt; if (cap < 0) cap = 0;
                float pden = 0.f, pnum = 0.f;
                int kn = 0;
#pragma unroll 1
                for (; kn < cap; ++kn) {
                    int j = s_nbr[i][kn];
                    const unsigned int* e = (const unsigned int*)(s_pool + (base + kn) * FEc);
                    uint4 p0 = *(const uint4*)e;
                    uint4 p1 = *(const uint4*)(e + 4);
                    float ep = bflo(p0.x)*wef[0]  + bfhi(p0.x)*wef[1]
                             + bflo(p0.y)*wef[2]  + bfhi(p0.y)*wef[3]
                             + bflo(p0.z)*wef[4]  + bfhi(p0.z)*wef[5]
                             + bflo(p0.w)*wef[6]  + bfhi(p0.w)*wef[7]
                             + bflo(p1.x)*wef[8]  + bfhi(p1.x)*wef[9]
                             + bflo(p1.y)*wef[10] + bfhi(p1.y)*wef[11]
                             + bflo(p1.z)*wef[12] + bfhi(p1.z)*wef[13]
                             + bflo(p1.w)*wef[14] + bfhi(p1.w)*wef[15];
                    float w = __expf(fast_tanh(ep + bf2f(s_npb[j * ROWP + m])));
                    pden += w;
                    pnum += w * bf2f(s_eb[j * ROWP + m]);
                }
#pragma unroll 1
                for (; kn < cnt; ++kn) {   // pool-overflow tail (statistically never)
                    int j = s_nbr[i][kn];
                    const float4* ef = (const float4*)(edges_b + ((size_t)i * Nc + j) * FEc);
                    float4 a0 = ef[0], a1 = ef[1], a2 = ef[2], a3 = ef[3];
                    float ep = a0.x*wef[0] + a0.y*wef[1] + a0.z*wef[2] + a0.w*wef[3]
                             + a1.x*wef[4] + a1.y*wef[5] + a1.z*wef[6] + a1.w*wef[7]
                             + a2.x*wef[8] + a2.y*wef[9] + a2.z*wef[10]+ a2.w*wef[11]
                             + a3.x*wef[12]+ a3.y*wef[13]+ a3.z*wef[14]+ a3.w*wef[15];
                    float w = __expf(fast_tanh(ep + bf2f(s_npb[j * ROWP + m])));
                    pden += w;
                    pnum += w * bf2f(s_eb[j * ROWP + m]);
                }
                s_mb[i * ROWP + m] = f2bf((cnt > 0) ? pnum * fast_rcp(pden) : 0.f);
            }
        }
        __syncthreads();

        // ---- GRU alpha: r,z gates (unroll-1 everywhere; 1 acc set live) ----
#pragma unroll 1
        for (int grp = 0; grp < 2; ++grp) {
            unsigned short* dst = grp ? s_eb : s_npb;   // np/emb dead after attention
            float bb = bi[grp * 128 + col] + bh[grp * 128 + col];
#pragma unroll 1
            for (int mt = 0; mt < 3; ++mt) {
                floatx4 acc = {0.f,0.f,0.f,0.f};
#pragma unroll 1
                for (int kt = 0; kt < 4; ++kt) {
                    acc = mm(afrag(s_mb, mt, kt, lane), bfrag(wWi, grp * 8 + wave, 4, kt, lane), acc);
                    acc = mm(afrag(s_hb, mt, kt, lane), bfrag(wWh, grp * 8 + wave, 4, kt, lane), acc);
                }
#pragma unroll
                for (int reg = 0; reg < 4; ++reg) {
                    int row = mt * 16 + quad * 4 + reg;
                    if (row < Nc) dst[row * ROWP + col] = f2bf(fast_sigmoid(acc[reg] + bb));
                }
            }
        }
        // ---- GRU beta: candidate + h update into hreg (regs private -> pre-barrier ok) ----
        // mt fully unrolled (hreg static indexing); kt unroll 1 (no load-hoist mass).
        {
            float bnI = bi[256 + col], bnH = bh[256 + col];
#pragma unroll
            for (int mt = 0; mt < 3; ++mt) {
                floatx4 ai = {0.f,0.f,0.f,0.f}, ah = {0.f,0.f,0.f,0.f};
#pragma unroll 1
                for (int kt = 0; kt < 4; ++kt) {
                    ai = mm(afrag(s_mb, mt, kt, lane), bfrag(wWi, 16 + wave, 4, kt, lane), ai);
                    ah = mm(afrag(s_hb, mt, kt, lane), bfrag(wWh, 16 + wave, 4, kt, lane), ah);
                }
#pragma unroll
                for (int reg = 0; reg < 4; ++reg) {
                    int row = mt * 16 + quad * 4 + reg;
                    if (row < Nc) {
                        float hold = hreg[mt][reg];
                        float r = bf2f(s_npb[row * ROWP + col]);
                        float z = bf2f(s_eb[row * ROWP + col]);
                        float n = fast_tanh(ai[reg] + bnI + r * (ah[reg] + bnH));
                        float v = (1.f - z) * n + z * hold;
                        hreg[mt][reg] = (s_cnt[row] > 0) ? v : hold;
                    }
                }
            }
        }
        __syncthreads();   // all afrag reads of s_hb complete before overwrite
#pragma unroll
        for (int mt = 0; mt < 3; ++mt)
#pragma unroll
            for (int reg = 0; reg < 4; ++reg) {
                int row = mt * 16 + quad * 4 + reg;
                if (row < Nc) s_hb[row * ROWP + col] = f2bf(hreg[mt][reg]);
            }
        __syncthreads();
    }

    // ---- Readout: out = sum_i mask * sigmoid(cat@Wg+bg) * (cat@Wo+bo) ----
    for (int idx = tid; idx < Nc * Hc; idx += T) {
        int row = idx >> 7, c2 = idx & 127;
        s_mb[row * ROWP + c2] = f2bf(nodes_b[idx]);   // cat tail (messages dead)
    }
    __syncthreads();
    float psum = 0.f;
    {
        float bgv = bg[col], bov = bo[col];
#pragma unroll 1
        for (int mt = 0; mt < 3; ++mt) {
            floatx4 ga = {0.f,0.f,0.f,0.f}, oa = {0.f,0.f,0.f,0.f};
#pragma unroll 1
            for (int kt = 0; kt < 8; ++kt) {
                short8 a = (kt < 4) ? afrag(s_hb, mt, kt, lane) : afrag(s_mb, mt, kt - 4, lane);
                ga = mm(a, bfrag(wWg, wave, 8, kt, lane), ga);
                oa = mm(a, bfrag(wWo, wave, 8, kt, lane), oa);
            }
#pragma unroll
            for (int reg = 0; reg < 4; ++reg) {
                int row = mt * 16 + quad * 4 + reg;
                if (row < Nc && s_cnt[row] > 0)
                    psum += fast_sigmoid(ga[reg] + bgv) * (oa[reg] + bov);
            }
        }
    }
    psum += __shfl_xor(psum, 16);   // reduce the 4 quads sharing this col
    psum += __shfl_xor(psum, 32);
    if (quad == 0) out[(size_t)b * OUTc + col] = psum;
}

extern "C" void kernel_launch(void* const* d_in, const int* in_sizes, int n_in,
                              void* d_out, int out_size, void* d_ws, size_t ws_size,
                              hipStream_t stream) {
    const float* nodes = (const float*)d_in[0];
    const float* edges = (const float*)d_in[1];
    const float* We = (const float*)d_in[2];
    const float* Wn = (const float*)d_in[3];
    const float* Wm = (const float*)d_in[4];
    const float* Wi = (const float*)d_in[5];
    const float* Wh = (const float*)d_in[6];
    const float* bi = (const float*)d_in[7];
    const float* bh = (const float*)d_in[8];
    const float* Wg = (const float*)d_in[9];
    const float* bg = (const float*)d_in[10];
    const float* Wo = (const float*)d_in[11];
    const float* bo = (const float*)d_in[12];
    float* out = (float*)d_out;
    unsigned short* ws = (unsigned short*)d_ws;

    prep_kernel<<<384, 64, 0, stream>>>(Wn, Wm, Wi, Wh, Wg, Wo, ws);
    mpnn_kernel<<<Bc, T, 0, stream>>>(nodes, edges, We, bi, bh, bg, bo, ws, out);
}

// Round 10
// 255.055 us; speedup vs baseline: 1.9825x; 1.0873x over previous
//
#include <hip/hip_runtime.h>

#define T 512
constexpr int Bc = 512, Nc = 40, Hc = 128, FEc = 16, Mc = 128, OUTc = 128, NPASS = 3;
constexpr int ROWP = 136;   // bf16 LDS row pitch (multiple of 8 for aligned b128 reads)
constexpr int EPOOL = 512;  // LDS edge pool slots (mean ~296, sigma ~22; fallback covers overflow)

typedef __attribute__((ext_vector_type(8))) short short8;
typedef __attribute__((ext_vector_type(4))) float floatx4;
typedef __attribute__((ext_vector_type(4))) float fvec4;

// ws layout (bf16 elements): fragment-major B operands only (384 KB, L2-resident)
constexpr int WS_WN = 0, WS_WM = 16384, WS_WI = 32768, WS_WH = 81920, WS_WG = 131072, WS_WO = 163840;

__device__ __forceinline__ float fast_rcp(float x) { return __builtin_amdgcn_rcpf(x); }
__device__ __forceinline__ float fast_sigmoid(float x) { return fast_rcp(1.f + __expf(-x)); }
__device__ __forceinline__ float fast_tanh(float x) {
    float t = __expf(2.f * x);
    return 1.f - 2.f * fast_rcp(t + 1.f);
}
__device__ __forceinline__ float bf2f(unsigned short u) {
    union { unsigned int i; float f; } v; v.i = ((unsigned int)u) << 16; return v.f;
}
__device__ __forceinline__ unsigned short f2bf(float f) {
    union { float f; unsigned int i; } v; v.f = f;
    unsigned int r = v.i + 0x7fff + ((v.i >> 16) & 1);   // RNE
    return (unsigned short)(r >> 16);
}

__device__ __forceinline__ floatx4 mm(short8 a, short8 b, floatx4 c) {
    return __builtin_amdgcn_mfma_f32_16x16x32_bf16(a, b, c, 0, 0, 0);
}
// A-fragment: A[m=lane&15][k=quad*8+j]; rows>=40 clamped (their C rows discarded)
__device__ __forceinline__ short8 afrag(const unsigned short* buf, int mt, int kt, int lane) {
    int row = mt * 16 + (lane & 15); row = row > 39 ? 39 : row;
    return *(const short8*)(buf + row * ROWP + kt * 32 + (lane >> 4) * 8);
}
__device__ __forceinline__ short8 bfrag(const unsigned short* w, int nt, int nKT, int kt, int lane) {
    return *(const short8*)(w + ((nt * nKT + kt) * 64 + lane) * 8);
}

// ---- prep: weights -> bf16 B-fragment layout in ws ----
__global__ void prep_kernel(const float* __restrict__ Wn, const float* __restrict__ Wm,
                            const float* __restrict__ Wi, const float* __restrict__ Wh,
                            const float* __restrict__ Wg, const float* __restrict__ Wo,
                            unsigned short* __restrict__ ws) {
    int c = blockIdx.x, lane = threadIdx.x;
    int quad = lane >> 4, l16 = lane & 15;
    const float* W; int N, nKT, local; unsigned short* dst;
    if (c < 32)       { W = Wn; N = 128; nKT = 4; local = c;       dst = ws + WS_WN; }
    else if (c < 64)  { W = Wm; N = 128; nKT = 4; local = c - 32;  dst = ws + WS_WM; }
    else if (c < 160) { W = Wi; N = 384; nKT = 4; local = c - 64;  dst = ws + WS_WI; }
    else if (c < 256) { W = Wh; N = 384; nKT = 4; local = c - 160; dst = ws + WS_WH; }
    else if (c < 320) { W = Wg; N = 128; nKT = 8; local = c - 256; dst = ws + WS_WG; }
    else              { W = Wo; N = 128; nKT = 8; local = c - 320; dst = ws + WS_WO; }
    int nt = local / nKT, kt = local % nKT;
    short8 v;
#pragma unroll
    for (int j = 0; j < 8; ++j) {
        int k = kt * 32 + quad * 8 + j;
        v[j] = (short)f2bf(W[k * N + nt * 16 + l16]);
    }
    *(short8*)(dst + local * 512 + lane * 8) = v;
}

// T=512, 8 waves, LDS ~78 KB -> 2 blocks/CU (4 waves/SIMD).
// Anti-spill rules (R9-proven): (1) attention reads LDS pool only; (2) GEMM mt/kt loops
// `#pragma unroll 1` so no region holds >2 B-frags in flight; (3) private arrays only
// in fully-unrolled code. R10: pool is fp32 (wave-uniform slot -> LDS broadcast, free),
// deleting 16 unpack insts from the 44-inst attention inner loop.
__global__ __launch_bounds__(T, 4) void mpnn_kernel(
    const float* __restrict__ nodes, const float* __restrict__ edges,
    const float* __restrict__ We, const float* __restrict__ bi,
    const float* __restrict__ bh, const float* __restrict__ bg,
    const float* __restrict__ bo, const unsigned short* __restrict__ ws,
    float* __restrict__ out)
{
    __shared__ __attribute__((aligned(16))) unsigned short s_hb[Nc * ROWP];   // bf16 h
    __shared__ __attribute__((aligned(16))) unsigned short s_mb[Nc * ROWP];   // messages / nodes(cat)
    __shared__ __attribute__((aligned(16))) unsigned short s_npb[Nc * ROWP];  // np, then r-gate
    __shared__ __attribute__((aligned(16))) unsigned short s_eb[Nc * ROWP];   // emb, then z (init: slot_src)
    __shared__ __attribute__((aligned(16))) float s_pool[EPOOL * FEc];        // 32 KB fp32 edge features
    __shared__ unsigned char s_nbr[Nc][Nc];
    __shared__ int s_cnt[Nc];
    __shared__ int s_off[Nc];
    __shared__ int s_total;

    const int b = blockIdx.x, tid = threadIdx.x;
    const int lane = tid & 63, wave = tid >> 6;          // 8 waves; nt = wave
    const int quad = lane >> 4, l16 = lane & 15;
    const int m = tid & 127, g = tid >> 7;               // attention: g in 0..3
    const int col = wave * 16 + l16;

    const float* nodes_b = nodes + (size_t)b * Nc * Hc;
    const float* edges_b = edges + (size_t)b * Nc * Nc * FEc;
    const unsigned short* wWn = ws + WS_WN; const unsigned short* wWm = ws + WS_WM;
    const unsigned short* wWi = ws + WS_WI; const unsigned short* wWh = ws + WS_WH;
    const unsigned short* wWg = ws + WS_WG; const unsigned short* wWo = ws + WS_WO;

    // ---- init: h fp32 in registers (static map, fully unrolled), bf16 in LDS ----
    float hreg[3][4];
#pragma unroll
    for (int mt = 0; mt < 3; ++mt)
#pragma unroll
        for (int reg = 0; reg < 4; ++reg) {
            int row = mt * 16 + quad * 4 + reg;
            float v = (row < Nc) ? nodes_b[row * Hc + col] : 0.f;
            hreg[mt][reg] = v;
            if (row < Nc) s_hb[row * ROWP + col] = f2bf(v);
        }
    // ---- adjacency scan (streaming, non-temporal) ----
    for (int p = tid; p < Nc * Nc; p += T) {
        const fvec4* e4 = (const fvec4*)(edges_b + p * FEc);
        fvec4 a0 = __builtin_nontemporal_load(e4);
        fvec4 a1 = __builtin_nontemporal_load(e4 + 1);
        fvec4 a2 = __builtin_nontemporal_load(e4 + 2);
        fvec4 a3 = __builtin_nontemporal_load(e4 + 3);
        float s = a0.x + a0.y + a0.z + a0.w + a1.x + a1.y + a1.z + a1.w
                + a2.x + a2.y + a2.z + a2.w + a3.x + a3.y + a3.z + a3.w;
        ((unsigned char*)s_nbr)[p] = (s > 0.f) ? 1 : 0;
    }
    __syncthreads();
    if (tid < Nc) {               // compact neighbor list in place
        int c = 0;
#pragma unroll 1
        for (int j = 0; j < Nc; ++j)
            if (s_nbr[tid][j]) { s_nbr[tid][c] = (unsigned char)j; ++c; }
        s_cnt[tid] = c;
    }
    __syncthreads();
    if (tid == 0) {
        int tot = 0;
#pragma unroll 1
        for (int i = 0; i < Nc; ++i) { s_off[i] = tot; tot += s_cnt[i]; }
        s_total = tot;
    }
    __syncthreads();
    int* slot_src = (int*)s_eb;   // temp alias; dead before pass-0 Phase A writes s_eb
    if (tid < Nc) {
        int base = s_off[tid], cnt = s_cnt[tid];
#pragma unroll 1
        for (int kn = 0; kn < cnt; ++kn) {
            int slot = base + kn;
            if (slot < EPOOL) slot_src[slot] = tid * Nc + s_nbr[tid][kn];
        }
    }
    __syncthreads();
    {   // fill compact fp32 edge pool (once; reused all 3 passes)
        const int E = s_total < EPOOL ? s_total : EPOOL;
#pragma unroll 1
        for (int w = tid; w < E * 4; w += T) {
            int s = w >> 2, q = w & 3;
            const float* src = edges_b + (size_t)slot_src[s] * FEc + q * 4;
            fvec4 x = __builtin_nontemporal_load((const fvec4*)src);
            *(fvec4*)(s_pool + s * FEc + q * 4) = x;
        }
    }
    __syncthreads();

    for (int pass = 0; pass < NPASS; ++pass) {
        // ---- Phase A: np = h@Wn, emb = h@Wm (bfr cached; mt loop unroll 1) ----
#pragma unroll 1
        for (int jb = 0; jb < 2; ++jb) {
            const unsigned short* wb = jb ? wWm : wWn;
            unsigned short* dst = jb ? s_eb : s_npb;
            short8 bfr[4];
#pragma unroll
            for (int kt = 0; kt < 4; ++kt) bfr[kt] = bfrag(wb, wave, 4, kt, lane);
#pragma unroll 1
            for (int mt = 0; mt < 3; ++mt) {
                floatx4 acc = {0.f, 0.f, 0.f, 0.f};
#pragma unroll
                for (int kt = 0; kt < 4; ++kt) acc = mm(afrag(s_hb, mt, kt, lane), bfr[kt], acc);
#pragma unroll
                for (int reg = 0; reg < 4; ++reg) {
                    int row = mt * 16 + quad * 4 + reg;
                    if (row < Nc) dst[row * ROWP + col] = f2bf(acc[reg]);
                }
            }
        }
        __syncthreads();

        // ---- Attention from fp32 LDS pool: ~28 VALU/edge, broadcast LDS reads ----
        {
            float wef[FEc];
#pragma unroll
            for (int f = 0; f < FEc; ++f) wef[f] = We[f * Mc + m];
#pragma unroll 1
            for (int ib = 0; ib < 10; ++ib) {
                int i = g + ib * 4;
                int cnt = s_cnt[i], base = s_off[i];
                int cap = EPOOL - base; if (cap > cnt) cap = cnt; if (cap < 0) cap = 0;
                float pden = 0.f, pnum = 0.f;
                int kn = 0;
#pragma unroll 1
                for (; kn < cap; ++kn) {
                    int j = s_nbr[i][kn];
                    const float* e = s_pool + (base + kn) * FEc;
                    fvec4 a0 = *(const fvec4*)e;
                    fvec4 a1 = *(const fvec4*)(e + 4);
                    fvec4 a2 = *(const fvec4*)(e + 8);
                    fvec4 a3 = *(const fvec4*)(e + 12);
                    float ep = a0.x*wef[0] + a0.y*wef[1] + a0.z*wef[2] + a0.w*wef[3]
                             + a1.x*wef[4] + a1.y*wef[5] + a1.z*wef[6] + a1.w*wef[7]
                             + a2.x*wef[8] + a2.y*wef[9] + a2.z*wef[10]+ a2.w*wef[11]
                             + a3.x*wef[12]+ a3.y*wef[13]+ a3.z*wef[14]+ a3.w*wef[15];
                    float w = __expf(fast_tanh(ep + bf2f(s_npb[j * ROWP + m])));
                    pden += w;
                    pnum += w * bf2f(s_eb[j * ROWP + m]);
                }
#pragma unroll 1
                for (; kn < cnt; ++kn) {   // pool-overflow tail (statistically never)
                    int j = s_nbr[i][kn];
                    const float4* ef = (const float4*)(edges_b + ((size_t)i * Nc + j) * FEc);
                    float4 a0 = ef[0], a1 = ef[1], a2 = ef[2], a3 = ef[3];
                    float ep = a0.x*wef[0] + a0.y*wef[1] + a0.z*wef[2] + a0.w*wef[3]
                             + a1.x*wef[4] + a1.y*wef[5] + a1.z*wef[6] + a1.w*wef[7]
                             + a2.x*wef[8] + a2.y*wef[9] + a2.z*wef[10]+ a2.w*wef[11]
                             + a3.x*wef[12]+ a3.y*wef[13]+ a3.z*wef[14]+ a3.w*wef[15];
                    float w = __expf(fast_tanh(ep + bf2f(s_npb[j * ROWP + m])));
                    pden += w;
                    pnum += w * bf2f(s_eb[j * ROWP + m]);
                }
                s_mb[i * ROWP + m] = f2bf((cnt > 0) ? pnum * fast_rcp(pden) : 0.f);
            }
        }
        __syncthreads();

        // ---- GRU alpha: r,z gates (unroll-1 everywhere; 1 acc set live) ----
#pragma unroll 1
        for (int grp = 0; grp < 2; ++grp) {
            unsigned short* dst = grp ? s_eb : s_npb;   // np/emb dead after attention
            float bb = bi[grp * 128 + col] + bh[grp * 128 + col];
#pragma unroll 1
            for (int mt = 0; mt < 3; ++mt) {
                floatx4 acc = {0.f,0.f,0.f,0.f};
#pragma unroll 1
                for (int kt = 0; kt < 4; ++kt) {
                    acc = mm(afrag(s_mb, mt, kt, lane), bfrag(wWi, grp * 8 + wave, 4, kt, lane), acc);
                    acc = mm(afrag(s_hb, mt, kt, lane), bfrag(wWh, grp * 8 + wave, 4, kt, lane), acc);
                }
#pragma unroll
                for (int reg = 0; reg < 4; ++reg) {
                    int row = mt * 16 + quad * 4 + reg;
                    if (row < Nc) dst[row * ROWP + col] = f2bf(fast_sigmoid(acc[reg] + bb));
                }
            }
        }
        // ---- GRU beta: candidate + h update into hreg (regs private -> pre-barrier ok) ----
        {
            float bnI = bi[256 + col], bnH = bh[256 + col];
#pragma unroll
            for (int mt = 0; mt < 3; ++mt) {
                floatx4 ai = {0.f,0.f,0.f,0.f}, ah = {0.f,0.f,0.f,0.f};
#pragma unroll 1
                for (int kt = 0; kt < 4; ++kt) {
                    ai = mm(afrag(s_mb, mt, kt, lane), bfrag(wWi, 16 + wave, 4, kt, lane), ai);
                    ah = mm(afrag(s_hb, mt, kt, lane), bfrag(wWh, 16 + wave, 4, kt, lane), ah);
                }
#pragma unroll
                for (int reg = 0; reg < 4; ++reg) {
                    int row = mt * 16 + quad * 4 + reg;
                    if (row < Nc) {
                        float hold = hreg[mt][reg];
                        float r = bf2f(s_npb[row * ROWP + col]);
                        float z = bf2f(s_eb[row * ROWP + col]);
                        float n = fast_tanh(ai[reg] + bnI + r * (ah[reg] + bnH));
                        float v = (1.f - z) * n + z * hold;
                        hreg[mt][reg] = (s_cnt[row] > 0) ? v : hold;
                    }
                }
            }
        }
        __syncthreads();   // all afrag reads of s_hb complete before overwrite
#pragma unroll
        for (int mt = 0; mt < 3; ++mt)
#pragma unroll
            for (int reg = 0; reg < 4; ++reg) {
                int row = mt * 16 + quad * 4 + reg;
                if (row < Nc) s_hb[row * ROWP + col] = f2bf(hreg[mt][reg]);
            }
        __syncthreads();
    }

    // ---- Readout: out = sum_i mask * sigmoid(cat@Wg+bg) * (cat@Wo+bo) ----
    for (int idx = tid; idx < Nc * Hc; idx += T) {
        int row = idx >> 7, c2 = idx & 127;
        s_mb[row * ROWP + c2] = f2bf(nodes_b[idx]);   // cat tail (messages dead)
    }
    __syncthreads();
    float psum = 0.f;
    {
        float bgv = bg[col], bov = bo[col];
#pragma unroll 1
        for (int mt = 0; mt < 3; ++mt) {
            floatx4 ga = {0.f,0.f,0.f,0.f}, oa = {0.f,0.f,0.f,0.f};
#pragma unroll 1
            for (int kt = 0; kt < 8; ++kt) {
                short8 a = (kt < 4) ? afrag(s_hb, mt, kt, lane) : afrag(s_mb, mt, kt - 4, lane);
                ga = mm(a, bfrag(wWg, wave, 8, kt, lane), ga);
                oa = mm(a, bfrag(wWo, wave, 8, kt, lane), oa);
            }
#pragma unroll
            for (int reg = 0; reg < 4; ++reg) {
                int row = mt * 16 + quad * 4 + reg;
                if (row < Nc && s_cnt[row] > 0)
                    psum += fast_sigmoid(ga[reg] + bgv) * (oa[reg] + bov);
            }
        }
    }
    psum += __shfl_xor(psum, 16);   // reduce the 4 quads sharing this col
    psum += __shfl_xor(psum, 32);
    if (quad == 0) out[(size_t)b * OUTc + col] = psum;
}

extern "C" void kernel_launch(void* const* d_in, const int* in_sizes, int n_in,
                              void* d_out, int out_size, void* d_ws, size_t ws_size,
                              hipStream_t stream) {
    const float* nodes = (const float*)d_in[0];
    const float* edges = (const float*)d_in[1];
    const float* We = (const float*)d_in[2];
    const float* Wn = (const float*)d_in[3];
    const float* Wm = (const float*)d_in[4];
    const float* Wi = (const float*)d_in[5];
    const float* Wh = (const float*)d_in[6];
    const float* bi = (const float*)d_in[7];
    const float* bh = (const float*)d_in[8];
    const float* Wg = (const float*)d_in[9];
    const float* bg = (const float*)d_in[10];
    const float* Wo = (const float*)d_in[11];
    const float* bo = (const float*)d_in[12];
    float* out = (float*)d_out;
    unsigned short* ws = (unsigned short*)d_ws;

    prep_kernel<<<384, 64, 0, stream>>>(Wn, Wm, Wi, Wh, Wg, Wo, ws);
    mpnn_kernel<<<Bc, T, 0, stream>>>(nodes, edges, We, bi, bh, bg, bo, ws, out);
}